// Round 13
// baseline (835.874 us; speedup 1.0000x reference)
//
#include <hip/hip_runtime.h>
#include <hip/hip_bf16.h>

#define DEV __device__ __forceinline__

typedef __attribute__((ext_vector_type(8))) short short8;
typedef __attribute__((ext_vector_type(4))) float f32x4;

DEV unsigned short f2bf(float f) {
    __hip_bfloat16 h = __float2bfloat16(f);
    unsigned short u;
    __builtin_memcpy(&u, &h, 2);
    return u;
}
DEV float bf2f(unsigned short u) { return __uint_as_float((unsigned int)u << 16); }

DEV f32x4 mfma_bf16(short8 a, short8 b, f32x4 c) {
    return __builtin_amdgcn_mfma_f32_16x16x32_bf16(a, b, c, 0, 0, 0);
}

// fp32 -> (hi, lo) bf16 pair; hi+lo represents v to ~2^-17 rel.
DEV void make_hilo(const float* a8, short8& hi, short8& lo) {
    #pragma unroll
    for (int j = 0; j < 8; ++j) {
        const float v = a8[j];
        const unsigned short h = f2bf(v);
        hi[j] = (short)h;
        lo[j] = (short)f2bf(v - bf2f(h));
    }
}

// 3-term split-precision MFMA accumulate against 4 column-frags.
DEV void mfma3(f32x4 acc[4], short8 ah, short8 al,
               const unsigned short* __restrict__ Bh,
               const unsigned short* __restrict__ Bl,
               int nkt, int tidx, int lane) {
    #pragma unroll
    for (int c = 0; c < 4; ++c) {
        const size_t o = ((size_t)(c * nkt + tidx) * 64 + lane) * 8;
        const short8 bh = *(const short8*)(Bh + o);
        const short8 bl = *(const short8*)(Bl + o);
        acc[c] = mfma_bf16(ah, bh, acc[c]);
        acc[c] = mfma_bf16(al, bh, acc[c]);
        acc[c] = mfma_bf16(ah, bl, acc[c]);
    }
}

// XOR-chunk-swizzled fp32 activation buffer (16 rows x 64)
DEV int swf(int row, int col) {
    return row * 64 + ((((col >> 3) ^ row) & 7) << 3) + (col & 7);
}

DEV void gemm_lds(f32x4 acc[4], const float* Xl,
                  const unsigned short* Bh, const unsigned short* Bl,
                  int nkt, int t0, int ntk, int l15, int q, int lane) {
    for (int t = 0; t < ntk; ++t) {
        const int ch = (t * 4 + q) ^ (l15 & 7);
        const float* a8 = Xl + l15 * 64 + ch * 8;
        short8 ah, al;
        make_hilo(a8, ah, al);
        mfma3(acc, ah, al, Bh, Bl, nkt, t0 + t, lane);
    }
}

DEV void gemm_glb(f32x4 acc[4], const float* __restrict__ Xg, int rbase, int N,
                  const unsigned short* Bh, const unsigned short* Bl,
                  int nkt, int t0, int ntk, int l15, int q, int lane) {
    const int grow = rbase + l15;
    const bool ok = grow < N;
    for (int t = 0; t < ntk; ++t) {
        float a8[8];
        if (ok) {
            const float4 v0 = *(const float4*)(Xg + (size_t)grow * 64 + t * 32 + q * 8);
            const float4 v1 = *(const float4*)(Xg + (size_t)grow * 64 + t * 32 + q * 8 + 4);
            a8[0] = v0.x; a8[1] = v0.y; a8[2] = v0.z; a8[3] = v0.w;
            a8[4] = v1.x; a8[5] = v1.y; a8[6] = v1.z; a8[7] = v1.w;
        } else {
            #pragma unroll
            for (int j = 0; j < 8; ++j) a8[j] = 0.f;
        }
        short8 ah, al;
        make_hilo(a8, ah, al);
        mfma3(acc, ah, al, Bh, Bl, nkt, t0 + t, lane);
    }
}

// ---------------------------------------------------------------------------
// Weight prep (unchanged)
// ---------------------------------------------------------------------------
#define NMAT 15
struct PrepArgs {
    const float* src[NMAT];
    unsigned short* hi[NMAT];
    unsigned short* lo[NMAT];
    int nkt[NMAT];
    int KR[NMAT];
};

__global__ __launch_bounds__(256)
void prep_kernel(PrepArgs pa)
{
    const int m = blockIdx.y;
    const int nkt = pa.nkt[m];
    const int nthr = nkt * 4 * 64;
    const int p = blockIdx.x * 256 + threadIdx.x;
    if (p >= nthr) return;
    const int f = p >> 6, l = p & 63;
    const int c = f / nkt, t = f % nkt;
    const int kbase = t * 32 + ((l >> 4) << 3);
    const int n = c * 16 + (l & 15);
    const float* W = pa.src[m];
    const int KR = pa.KR[m];
    unsigned short* ph = pa.hi[m] + (size_t)p * 8;
    unsigned short* pl = pa.lo[m] + (size_t)p * 8;
    #pragma unroll
    for (int j = 0; j < 8; ++j) {
        const int k = kbase + j;
        const float v = (k < KR) ? W[k * 64 + n] : 0.f;
        const unsigned short h = f2bf(v);
        ph[j] = h;
        pl[j] = f2bf(v - bf2f(h));
    }
}

// ---------------------------------------------------------------------------
// Fused hist(+rank) / embed kernel (16 KB LDS — unchanged from R12).
// ---------------------------------------------------------------------------
struct FusedArgs {
    const int* ei; int E; int nH;
    int* h1; int* h2; unsigned int* rank;
    int tC, tV;
    const float* cf; int NC;
    const float* c_shift; const float* c_scale;
    const float* vf; int NV;
    const float* v_shift; const float* v_scale;
    const unsigned short *cW1h, *cW1l, *cW2h, *cW2l, *cWt1h, *cWt1l;
    const unsigned short *vW1h, *vW1l, *vW2h, *vW2l, *vWt1h, *vWt1l, *vWt2h, *vWt2l;
    const float *c_b1, *c_b2, *v_b1, *v_b2, *vc_bl;
    const float *vc_sf, *cv_sf;
    float* Emc; float* Emv;
    unsigned short* A1; unsigned short* B1; unsigned short* B2;
};

__global__ __launch_bounds__(256)
void fused_he_kernel(FusedArgs a)
{
    __shared__ __align__(16) float Bb[4][1024];   // Hb, then reused as Eb

    const int half = blockIdx.x & 1;
    const int idx  = blockIdx.x >> 1;

    if (half == 0) {
        const int stride = a.nH * 256;
        for (int e = idx * 256 + (int)threadIdx.x; e < a.E; e += stride) {
            const int r1 = atomicAdd(a.h1 + a.ei[e], 1);
            const int r2 = atomicAdd(a.h2 + a.ei[a.E + e], 1);
            a.rank[e] = (unsigned int)r1 | ((unsigned int)r2 << 16);
        }
        return;
    }

    int tile = idx;
    const float* x; int N; int IN;
    const float *shift, *scale, *b1, *b2, *bt1;
    const unsigned short *W1h, *W1l, *W2h, *W2l, *Wt1h, *Wt1l;
    const unsigned short *Wt2h = nullptr, *Wt2l = nullptr;
    float* Em; unsigned short* T1; unsigned short* T2 = nullptr;
    float sf1, sf2 = 0.f;
    if (tile < a.tC) {
        x = a.cf; N = a.NC; IN = 5; shift = a.c_shift; scale = a.c_scale;
        W1h = a.cW1h; W1l = a.cW1l; b1 = a.c_b1;
        W2h = a.cW2h; W2l = a.cW2l; b2 = a.c_b2;
        Em = a.Emc; Wt1h = a.cWt1h; Wt1l = a.cWt1l; bt1 = a.vc_bl;
        sf1 = a.vc_sf[0]; T1 = a.A1;
    } else {
        tile -= a.tC;
        x = a.vf; N = a.NV; IN = 19; shift = a.v_shift; scale = a.v_scale;
        W1h = a.vW1h; W1l = a.vW1l; b1 = a.v_b1;
        W2h = a.vW2h; W2l = a.vW2l; b2 = a.v_b2;
        Em = a.Emv; Wt1h = a.vWt1h; Wt1l = a.vWt1l; bt1 = nullptr;
        sf1 = a.vc_sf[0]; T1 = a.B1;
        Wt2h = a.vWt2h; Wt2l = a.vWt2l; sf2 = a.cv_sf[0]; T2 = a.B2;
    }

    const int w = threadIdx.x >> 6, lane = threadIdx.x & 63;
    const int l15 = lane & 15, q = lane >> 4;
    const int rbase = tile * 64 + w * 16;

    {
        f32x4 acc[4] = {{0,0,0,0},{0,0,0,0},{0,0,0,0},{0,0,0,0}};
        const int grow = rbase + l15;
        float a8[8];
        #pragma unroll
        for (int j = 0; j < 8; ++j) {
            const int col = q * 8 + j;
            float v = 0.f;
            if (grow < N && col < IN) v = (x[(size_t)grow * IN + col] - shift[col]) * scale[col];
            a8[j] = v;
        }
        short8 ah, al;
        make_hilo(a8, ah, al);
        mfma3(acc, ah, al, W1h, W1l, 1, 0, lane);
        #pragma unroll
        for (int c = 0; c < 4; ++c) {
            const int col = c * 16 + l15;
            const float bb = b1[col];
            #pragma unroll
            for (int r = 0; r < 4; ++r)
                Bb[w][swf(q * 4 + r, col)] = fmaxf(acc[c][r] + bb, 0.f);
        }
    }
    {
        f32x4 acc[4] = {{0,0,0,0},{0,0,0,0},{0,0,0,0},{0,0,0,0}};
        gemm_lds(acc, Bb[w], W2h, W2l, 2, 0, 2, l15, q, lane);
        #pragma unroll
        for (int c = 0; c < 4; ++c) {
            const int col = c * 16 + l15;
            const float bb = b2[col];
            #pragma unroll
            for (int r = 0; r < 4; ++r) {
                const int row = q * 4 + r;
                const int grow = rbase + row;
                const float v = fmaxf(acc[c][r] + bb, 0.f);
                Bb[w][swf(row, col)] = v;
                if (grow < N) Em[(size_t)grow * 64 + col] = v;
            }
        }
    }
    {
        f32x4 acc[4] = {{0,0,0,0},{0,0,0,0},{0,0,0,0},{0,0,0,0}};
        gemm_lds(acc, Bb[w], Wt1h, Wt1l, 2, 0, 2, l15, q, lane);
        #pragma unroll
        for (int c = 0; c < 4; ++c) {
            const int col = c * 16 + l15;
            const float bb = bt1 ? bt1[col] : 0.f;
            #pragma unroll
            for (int r = 0; r < 4; ++r) {
                const int grow = rbase + q * 4 + r;
                if (grow < N) T1[(size_t)grow * 64 + col] = f2bf(sf1 * (acc[c][r] + bb));
            }
        }
    }
    if (T2 != nullptr) {
        f32x4 acc[4] = {{0,0,0,0},{0,0,0,0},{0,0,0,0},{0,0,0,0}};
        gemm_lds(acc, Bb[w], Wt2h, Wt2l, 2, 0, 2, l15, q, lane);
        #pragma unroll
        for (int c = 0; c < 4; ++c) {
            const int col = c * 16 + l15;
            #pragma unroll
            for (int r = 0; r < 4; ++r) {
                const int grow = rbase + q * 4 + r;
                if (grow < N) T2[(size_t)grow * 64 + col] = f2bf(sf2 * acc[c][r]);
            }
        }
    }
}

// ---------------------------------------------------------------------------
// Fused gather-aggregate + post-conv. Each block owns a 64-row tile; each
// wave gathers its 16 rows' G directly into LDS BA[w] (swf layout,
// wave-private -> no barrier), then runs the 4-layer post chain from LDS.
// agg phase is gather-latency-bound, post phase MFMA-bound -> inter-block
// overlap. A1<->A2 alias safe: each block reads A1/B2 for its own rows only
// and writes A2 for the same rows strictly after.
// ---------------------------------------------------------------------------
template<bool IS_POST2>
__global__ __launch_bounds__(256)
void aggpost_kernel(int N, const int* __restrict__ rs,
                    const int2* __restrict__ pairs,
                    const unsigned short* __restrict__ Ttgt,
                    const unsigned short* __restrict__ Tsrc,
                    const float* __restrict__ We, const float* __restrict__ sfp,
                    const float* __restrict__ Em,
                    const unsigned short* __restrict__ Wfh, const unsigned short* __restrict__ Wfl,
                    const float* __restrict__ bfv, const float* __restrict__ spp,
                    const unsigned short* __restrict__ Woah, const unsigned short* __restrict__ Woal,
                    const float* __restrict__ boa,
                    const unsigned short* __restrict__ Wobh, const unsigned short* __restrict__ Wobl,
                    const float* __restrict__ bob,
                    const unsigned short* __restrict__ W4h, const unsigned short* __restrict__ W4l,
                    const float* __restrict__ b4,
                    const float* __restrict__ sf2p, unsigned short* __restrict__ A2,
                    const float* __restrict__ oW2, float* __restrict__ out)
{
    __shared__ __align__(16) float BA[4][1024];
    __shared__ __align__(16) float BB[4][1024];

    const int w = threadIdx.x >> 6, lane = threadIdx.x & 63;
    const int l15 = lane & 15, q = lane >> 4;
    const float sp = spp[0];
    const float sf2 = IS_POST2 ? 0.f : sf2p[0];
    const int rbase = blockIdx.x * 64 + w * 16;

    // ---- agg phase: gather 16 rows' G into BA[w] (lane = channel) ----
    {
        const float sfWe = sfp[0] * We[lane];
        for (int r16 = 0; r16 < 16; ++r16) {
            const int row = rbase + r16;
            float acc = 0.f;
            if (row < N) {
                const float base = bf2f(Ttgt[(size_t)row * 64 + lane]);
                const int s = rs[row];
                const int e = rs[row + 1];
                int p = s;
                for (; p + 7 < e; p += 8) {
                    int2 a[8];
                    float b[8];
                    #pragma unroll
                    for (int u = 0; u < 8; ++u) a[u] = pairs[p + u];
                    #pragma unroll
                    for (int u = 0; u < 8; ++u)
                        b[u] = bf2f(Tsrc[(size_t)a[u].x * 64 + lane]);
                    #pragma unroll
                    for (int u = 0; u < 8; ++u)
                        acc += fmaxf(base + b[u] + __int_as_float(a[u].y) * sfWe, 0.f);
                }
                for (; p < e; ++p) {
                    const int2 pr = pairs[p];
                    const float bs = bf2f(Tsrc[(size_t)pr.x * 64 + lane]);
                    acc += fmaxf(base + bs + __int_as_float(pr.y) * sfWe, 0.f);
                }
            }
            BA[w][swf(r16, lane)] = acc;
        }
    }

    // ---- post phase (from LDS; BA overwritten in-place after L1 reads) ----
    {
        f32x4 acc[4] = {{0,0,0,0},{0,0,0,0},{0,0,0,0},{0,0,0,0}};
        gemm_lds(acc, BA[w], Wfh, Wfl, 2, 0, 2, l15, q, lane);
        float dgr[4];
        #pragma unroll
        for (int r = 0; r < 4; ++r) {
            const int grow = rbase + q * 4 + r;
            dgr[r] = (grow < N) ? (float)(rs[grow + 1] - rs[grow]) : 0.f;
        }
        #pragma unroll
        for (int c = 0; c < 4; ++c) {
            const int col = c * 16 + l15;
            const float bb = bfv[col];
            #pragma unroll
            for (int r = 0; r < 4; ++r)
                BA[w][swf(q * 4 + r, col)] = (acc[c][r] + dgr[r] * bb) * sp;
        }
    }
    {
        f32x4 acc[4] = {{0,0,0,0},{0,0,0,0},{0,0,0,0},{0,0,0,0}};
        gemm_lds(acc, BA[w], Woah, Woal, 4, 0, 2, l15, q, lane);
        gemm_glb(acc, Em, rbase, N, Woah, Woal, 4, 2, 2, l15, q, lane);
        #pragma unroll
        for (int c = 0; c < 4; ++c) {
            const int col = c * 16 + l15;
            const float bb = boa[col];
            #pragma unroll
            for (int r = 0; r < 4; ++r)
                BB[w][swf(q * 4 + r, col)] = fmaxf(acc[c][r] + bb, 0.f);
        }
    }
    {
        f32x4 acc[4] = {{0,0,0,0},{0,0,0,0},{0,0,0,0},{0,0,0,0}};
        gemm_lds(acc, BB[w], Wobh, Wobl, 2, 0, 2, l15, q, lane);
        #pragma unroll
        for (int c = 0; c < 4; ++c) {
            const int col = c * 16 + l15;
            const float bb = bob[col];
            #pragma unroll
            for (int r = 0; r < 4; ++r)
                BA[w][swf(q * 4 + r, col)] = fmaxf(acc[c][r] + bb, 0.f);
        }
    }
    {
        f32x4 acc[4] = {{0,0,0,0},{0,0,0,0},{0,0,0,0},{0,0,0,0}};
        gemm_lds(acc, BA[w], W4h, W4l, 2, 0, 2, l15, q, lane);
        if (!IS_POST2) {
            #pragma unroll
            for (int c = 0; c < 4; ++c) {
                const int col = c * 16 + l15;
                const float bb = b4[col];
                #pragma unroll
                for (int r = 0; r < 4; ++r) {
                    const int grow = rbase + q * 4 + r;
                    if (grow < N) A2[(size_t)grow * 64 + col] = f2bf(sf2 * (acc[c][r] + bb));
                }
            }
        } else {
            float w2c[4], bb4[4];
            #pragma unroll
            for (int c = 0; c < 4; ++c) {
                const int col = c * 16 + l15;
                w2c[c] = oW2[col];
                bb4[c] = b4[col];
            }
            #pragma unroll
            for (int r = 0; r < 4; ++r) {
                float s = 0.f;
                #pragma unroll
                for (int c = 0; c < 4; ++c)
                    s += fmaxf(acc[c][r] + bb4[c], 0.f) * w2c[c];
                s += __shfl_xor(s, 1);
                s += __shfl_xor(s, 2);
                s += __shfl_xor(s, 4);
                s += __shfl_xor(s, 8);
                const int grow = rbase + q * 4 + r;
                if (l15 == 0 && grow < N) out[grow] = s;
            }
        }
    }
}

// ---------------------------------------------------------------------------
// Multiblock scans (unchanged from R12)
// ---------------------------------------------------------------------------
__global__ __launch_bounds__(256)
void scanA2_kernel(const int* __restrict__ h1, int n1, int* __restrict__ cs1,
                   const int* __restrict__ h2, int n2, int* __restrict__ cs2)
{
    __shared__ int wsum[4];
    const int which = blockIdx.y;
    const int* h = which ? h2 : h1;
    const int n = which ? n2 : n1;
    int* csum = which ? cs2 : cs1;
    if (blockIdx.x * 4096 >= n) return;

    const int t = threadIdx.x, lane = t & 63, wid = t >> 6;
    const int base = blockIdx.x * 4096 + t * 16;
    int s = 0;
    #pragma unroll
    for (int j = 0; j < 16; ++j) {
        const int idx = base + j;
        if (idx < n) s += h[idx];
    }
    #pragma unroll
    for (int d = 1; d < 64; d <<= 1) s += __shfl_xor(s, d);
    if (lane == 0) wsum[wid] = s;
    __syncthreads();
    if (t == 0) csum[blockIdx.x] = wsum[0] + wsum[1] + wsum[2] + wsum[3];
}

__global__ __launch_bounds__(256)
void scanB2_kernel(int* __restrict__ cs1, int nch1, int* __restrict__ rs1, int n1,
                   int* __restrict__ cs2, int nch2, int* __restrict__ rs2, int n2)
{
    __shared__ int wsum[4];
    const int which = blockIdx.x;
    int* csum = which ? cs2 : cs1;
    const int nchunks = which ? nch2 : nch1;
    int* rs = which ? rs2 : rs1;
    const int n = which ? n2 : n1;

    const int t = threadIdx.x, lane = t & 63, wid = t >> 6;
    const int v = (t < nchunks) ? csum[t] : 0;
    int x = v;
    #pragma unroll
    for (int d = 1; d < 64; d <<= 1) { int y = __shfl_up(x, d); if (lane >= d) x += y; }
    if (lane == 63) wsum[wid] = x;
    __syncthreads();
    int woff = 0;
    for (int i = 0; i < wid; ++i) woff += wsum[i];
    if (t < nchunks) csum[t] = woff + x - v;
    if (t == 0) rs[n] = wsum[0] + wsum[1] + wsum[2] + wsum[3];
}

__global__ __launch_bounds__(256)
void scanC2_kernel(const int* __restrict__ h1, int n1, const int* __restrict__ cs1,
                   int* __restrict__ rs1,
                   const int* __restrict__ h2, int n2, const int* __restrict__ cs2,
                   int* __restrict__ rs2)
{
    __shared__ int wsum[4];
    const int which = blockIdx.y;
    const int* h = which ? h2 : h1;
    const int n = which ? n2 : n1;
    const int* csum = which ? cs2 : cs1;
    int* rs = which ? rs2 : rs1;
    if (blockIdx.x * 4096 >= n) return;

    const int t = threadIdx.x, lane = t & 63, wid = t >> 6;
    const int base = blockIdx.x * 4096 + t * 16;
    int loc[16];
    int s = 0;
    #pragma unroll
    for (int j = 0; j < 16; ++j) {
        loc[j] = s;
        const int idx = base + j;
        if (idx < n) s += h[idx];
    }
    int x = s;
    #pragma unroll
    for (int d = 1; d < 64; d <<= 1) { int y = __shfl_up(x, d); if (lane >= d) x += y; }
    if (lane == 63) wsum[wid] = x;
    __syncthreads();
    int woff = 0;
    for (int i = 0; i < wid; ++i) woff += wsum[i];
    const int toff = csum[blockIdx.x] + woff + x - s;
    #pragma unroll
    for (int j = 0; j < 16; ++j) {
        const int idx = base + j;
        if (idx < n) rs[idx] = toff + loc[j];
    }
}

// ---------------------------------------------------------------------------
// Atomic-free single-pass scatter (unchanged from R12)
// ---------------------------------------------------------------------------
__global__ __launch_bounds__(256)
void scatter_kernel(const int* __restrict__ ei, int E,
                    const float* __restrict__ ef,
                    const float* __restrict__ eshp, const float* __restrict__ escp,
                    const unsigned int* __restrict__ rank,
                    const int* __restrict__ rs1, const int* __restrict__ rs2,
                    int2* __restrict__ pairs1, int2* __restrict__ pairs2)
{
    const int e = blockIdx.x * 256 + threadIdx.x;
    if (e >= E) return;
    const int i0 = ei[e];
    const int i1 = ei[E + e];
    const unsigned int rk = rank[e];
    const float en = (ef[e] - eshp[0]) * escp[0];
    const int enb = __float_as_int(en);
    const int pos1 = rs1[i0] + (int)(rk & 0xffffu);
    const int pos2 = rs2[i1] + (int)(rk >> 16);
    pairs1[pos1] = make_int2(i1, enb);
    pairs2[pos2] = make_int2(i0, enb);
}

// ---------------------------------------------------------------------------
extern "C" void kernel_launch(void* const* d_in, const int* in_sizes, int n_in,
                              void* d_out, int out_size, void* d_ws, size_t ws_size,
                              hipStream_t stream)
{
    const float* cf      = (const float*)d_in[0];
    const float* ef      = (const float*)d_in[1];
    const float* vf      = (const float*)d_in[2];
    const float* c_shift = (const float*)d_in[3];
    const float* c_scale = (const float*)d_in[4];
    const float* v_shift = (const float*)d_in[5];
    const float* v_scale = (const float*)d_in[6];
    const float* e_shift = (const float*)d_in[7];
    const float* e_scale = (const float*)d_in[8];
    const float* c_W1 = (const float*)d_in[9];
    const float* c_b1 = (const float*)d_in[10];
    const float* c_W2 = (const float*)d_in[11];
    const float* c_b2 = (const float*)d_in[12];
    const float* v_W1 = (const float*)d_in[13];
    const float* v_b1 = (const float*)d_in[14];
    const float* v_W2 = (const float*)d_in[15];
    const float* v_b2 = (const float*)d_in[16];
    const float* vc_Wl  = (const float*)d_in[17];
    const float* vc_bl  = (const float*)d_in[18];
    const float* vc_We  = (const float*)d_in[19];
    const float* vc_Wr  = (const float*)d_in[20];
    const float* vc_sf  = (const float*)d_in[21];
    const float* vc_Wf  = (const float*)d_in[22];
    const float* vc_bf  = (const float*)d_in[23];
    const float* vc_sp  = (const float*)d_in[24];
    const float* vc_Woa = (const float*)d_in[25];
    const float* vc_boa = (const float*)d_in[26];
    const float* vc_Wob = (const float*)d_in[27];
    const float* vc_bob = (const float*)d_in[28];
    const float* cv_Wl  = (const float*)d_in[29];
    const float* cv_bl  = (const float*)d_in[30];
    const float* cv_We  = (const float*)d_in[31];
    const float* cv_Wr  = (const float*)d_in[32];
    const float* cv_sf  = (const float*)d_in[33];
    const float* cv_Wf  = (const float*)d_in[34];
    const float* cv_bf  = (const float*)d_in[35];
    const float* cv_sp  = (const float*)d_in[36];
    const float* cv_Woa = (const float*)d_in[37];
    const float* cv_boa = (const float*)d_in[38];
    const float* cv_Wob = (const float*)d_in[39];
    const float* cv_bob = (const float*)d_in[40];
    const float* out_W1 = (const float*)d_in[41];
    const float* out_b1 = (const float*)d_in[42];
    const float* out_W2 = (const float*)d_in[43];
    const int*   eidx   = (const int*)d_in[44];

    const int NC = in_sizes[0] / 5;
    const int NV = in_sizes[2] / 19;
    const int E  = in_sizes[1];

    // ---- workspace layout (256B aligned slots) ----
    // G1/G2 eliminated (agg+post fused through LDS); rank gets its own slot.
    char* ws = (char*)d_ws;
    size_t off = 0;
    auto alloc = [&](size_t bytes) -> size_t {
        size_t o = off;
        off = (off + bytes + 255) & ~(size_t)255;
        return o;
    };
    size_t o_h1 = alloc((size_t)NC * 4);
    size_t o_h2 = alloc((size_t)NV * 4);
    size_t zero_bytes = off;
    size_t o_rs1  = alloc((size_t)(NC + 1) * 4);
    size_t o_rs2  = alloc((size_t)(NV + 1) * 4);
    size_t o_cs1  = alloc(256 * 4);
    size_t o_cs2  = alloc(256 * 4);
    size_t o_rank = alloc((size_t)E * 4);
    size_t o_p1   = alloc((size_t)E * 8);
    size_t o_p2   = alloc((size_t)E * 8);
    size_t o_Emc  = alloc((size_t)NC * 64 * 4);
    size_t o_Emv  = alloc((size_t)NV * 64 * 4);
    size_t o_A1   = alloc((size_t)NC * 64 * 2);  // A2 aliases A1 (per-row RAW within owning block only)
    size_t o_B1   = alloc((size_t)NV * 64 * 2);
    size_t o_B2   = alloc((size_t)NV * 64 * 2);

    static const int nkt_arr[NMAT] = {1,2,2,1,2,2,2,2,4,2,2,2,4,2,2};
    static const int KR_arr[NMAT]  = {5,64,64,19,64,64,64,64,128,64,64,64,128,64,64};
    const float* src_arr[NMAT] = {c_W1, c_W2, vc_Wl, v_W1, v_W2, vc_Wr, cv_Wr,
                                  vc_Wf, vc_Woa, vc_Wob, cv_Wl,
                                  cv_Wf, cv_Woa, cv_Wob, out_W1};
    size_t o_wh[NMAT], o_wl[NMAT];
    for (int m = 0; m < NMAT; ++m) {
        o_wh[m] = alloc((size_t)nkt_arr[m] * 4 * 64 * 8 * 2);
        o_wl[m] = alloc((size_t)nkt_arr[m] * 4 * 64 * 8 * 2);
    }
    (void)ws_size; (void)n_in; (void)out_size;

    int*  h1   = (int*)(ws + o_h1);
    int*  h2   = (int*)(ws + o_h2);
    int*  rs1  = (int*)(ws + o_rs1);
    int*  rs2  = (int*)(ws + o_rs2);
    int*  cs1  = (int*)(ws + o_cs1);
    int*  cs2  = (int*)(ws + o_cs2);
    unsigned int* rank = (unsigned int*)(ws + o_rank);
    int2* p1   = (int2*)(ws + o_p1);
    int2* p2   = (int2*)(ws + o_p2);
    float* Emc = (float*)(ws + o_Emc);
    float* Emv = (float*)(ws + o_Emv);
    unsigned short* A1 = (unsigned short*)(ws + o_A1);
    unsigned short* B1 = (unsigned short*)(ws + o_B1);
    unsigned short* A2 = (unsigned short*)(ws + o_A1);  // alias
    unsigned short* B2 = (unsigned short*)(ws + o_B2);

    PrepArgs pa;
    for (int m = 0; m < NMAT; ++m) {
        pa.src[m] = src_arr[m];
        pa.hi[m] = (unsigned short*)(ws + o_wh[m]);
        pa.lo[m] = (unsigned short*)(ws + o_wl[m]);
        pa.nkt[m] = nkt_arr[m];
        pa.KR[m] = KR_arr[m];
    }
    auto WH = [&](int m) { return (const unsigned short*)(ws + o_wh[m]); };
    auto WL = [&](int m) { return (const unsigned short*)(ws + o_wl[m]); };

    hipMemsetAsync(ws, 0, zero_bytes, stream);

    // --- weight prep ---
    prep_kernel<<<dim3(4, NMAT), 256, 0, stream>>>(pa);

    // --- fused histogram(+rank) / embeddings ---
    const int tC = (NC + 63) >> 6, tV = (NV + 63) >> 6;
    const int nE = tC + tV;
    FusedArgs fa;
    fa.ei = eidx; fa.E = E; fa.nH = nE;
    fa.h1 = h1; fa.h2 = h2; fa.rank = rank;
    fa.tC = tC; fa.tV = tV;
    fa.cf = cf; fa.NC = NC; fa.c_shift = c_shift; fa.c_scale = c_scale;
    fa.vf = vf; fa.NV = NV; fa.v_shift = v_shift; fa.v_scale = v_scale;
    fa.cW1h = WH(0); fa.cW1l = WL(0); fa.cW2h = WH(1); fa.cW2l = WL(1);
    fa.cWt1h = WH(2); fa.cWt1l = WL(2);
    fa.vW1h = WH(3); fa.vW1l = WL(3); fa.vW2h = WH(4); fa.vW2l = WL(4);
    fa.vWt1h = WH(5); fa.vWt1l = WL(5); fa.vWt2h = WH(6); fa.vWt2l = WL(6);
    fa.c_b1 = c_b1; fa.c_b2 = c_b2; fa.v_b1 = v_b1; fa.v_b2 = v_b2;
    fa.vc_bl = vc_bl; fa.vc_sf = vc_sf; fa.cv_sf = cv_sf;
    fa.Emc = Emc; fa.Emv = Emv; fa.A1 = A1; fa.B1 = B1; fa.B2 = B2;
    fused_he_kernel<<<2 * nE, 256, 0, stream>>>(fa);

    // --- fused scans ---
    const int nch1 = (NC + 4095) / 4096, nch2 = (NV + 4095) / 4096;
    const int nchm = nch1 > nch2 ? nch1 : nch2;
    scanA2_kernel<<<dim3(nchm, 2), 256, 0, stream>>>(h1, NC, cs1, h2, NV, cs2);
    scanB2_kernel<<<2, 256, 0, stream>>>(cs1, nch1, rs1, NC, cs2, nch2, rs2, NV);
    scanC2_kernel<<<dim3(nchm, 2), 256, 0, stream>>>(h1, NC, cs1, rs1, h2, NV, cs2, rs2);

    // --- atomic-free single-pass scatter ---
    scatter_kernel<<<(E + 255) / 256, 256, 0, stream>>>(
        eidx, E, ef, e_shift, e_scale, rank, rs1, rs2, p1, p2);

    // --- conv1: fused agg+post (target ei0 -> Ttgt=A1, Tsrc=B1) -> A2 ---
    aggpost_kernel<false><<<tC, 256, 0, stream>>>(
        NC, rs1, p1, A1, B1, vc_We, vc_sf, Emc,
        WH(7), WL(7), vc_bf, vc_sp,
        WH(8), WL(8), vc_boa,
        WH(9), WL(9), vc_bob,
        WH(10), WL(10), cv_bl,
        cv_sf, A2, nullptr, nullptr);

    // --- conv2: fused agg+post (target ei1 -> Ttgt=B2, Tsrc=A2) -> out ---
    aggpost_kernel<true><<<tV, 256, 0, stream>>>(
        NV, rs2, p2, B2, A2, cv_We, cv_sf, Emv,
        WH(11), WL(11), cv_bf, cv_sp,
        WH(12), WL(12), cv_boa,
        WH(13), WL(13), cv_bob,
        WH(14), WL(14), out_b1,
        nullptr, nullptr, out_W2, (float*)d_out);
}

// Round 14
// 787.760 us; speedup vs baseline: 1.0611x; 1.0611x over previous
//
#include <hip/hip_runtime.h>
#include <hip/hip_bf16.h>

#define DEV __device__ __forceinline__

typedef __attribute__((ext_vector_type(8))) short short8;
typedef __attribute__((ext_vector_type(4))) float f32x4;

DEV unsigned short f2bf(float f) {
    __hip_bfloat16 h = __float2bfloat16(f);
    unsigned short u;
    __builtin_memcpy(&u, &h, 2);
    return u;
}
DEV float bf2f(unsigned short u) { return __uint_as_float((unsigned int)u << 16); }

DEV f32x4 mfma_bf16(short8 a, short8 b, f32x4 c) {
    return __builtin_amdgcn_mfma_f32_16x16x32_bf16(a, b, c, 0, 0, 0);
}

// fp32 -> (hi, lo) bf16 pair; hi+lo represents v to ~2^-17 rel.
DEV void make_hilo(const float* a8, short8& hi, short8& lo) {
    #pragma unroll
    for (int j = 0; j < 8; ++j) {
        const float v = a8[j];
        const unsigned short h = f2bf(v);
        hi[j] = (short)h;
        lo[j] = (short)f2bf(v - bf2f(h));
    }
}

// 3-term split-precision MFMA accumulate against 4 column-frags.
DEV void mfma3(f32x4 acc[4], short8 ah, short8 al,
               const unsigned short* __restrict__ Bh,
               const unsigned short* __restrict__ Bl,
               int nkt, int tidx, int lane) {
    #pragma unroll
    for (int c = 0; c < 4; ++c) {
        const size_t o = ((size_t)(c * nkt + tidx) * 64 + lane) * 8;
        const short8 bh = *(const short8*)(Bh + o);
        const short8 bl = *(const short8*)(Bl + o);
        acc[c] = mfma_bf16(ah, bh, acc[c]);
        acc[c] = mfma_bf16(al, bh, acc[c]);
        acc[c] = mfma_bf16(ah, bl, acc[c]);
    }
}

// XOR-chunk-swizzled fp32 activation buffer (16 rows x 64)
DEV int swf(int row, int col) {
    return row * 64 + ((((col >> 3) ^ row) & 7) << 3) + (col & 7);
}

DEV void gemm_lds(f32x4 acc[4], const float* Xl,
                  const unsigned short* Bh, const unsigned short* Bl,
                  int nkt, int t0, int ntk, int l15, int q, int lane) {
    for (int t = 0; t < ntk; ++t) {
        const int ch = (t * 4 + q) ^ (l15 & 7);
        const float* a8 = Xl + l15 * 64 + ch * 8;
        short8 ah, al;
        make_hilo(a8, ah, al);
        mfma3(acc, ah, al, Bh, Bl, nkt, t0 + t, lane);
    }
}

DEV void gemm_glb(f32x4 acc[4], const float* __restrict__ Xg, int rbase, int N,
                  const unsigned short* Bh, const unsigned short* Bl,
                  int nkt, int t0, int ntk, int l15, int q, int lane) {
    const int grow = rbase + l15;
    const bool ok = grow < N;
    for (int t = 0; t < ntk; ++t) {
        float a8[8];
        if (ok) {
            const float4 v0 = *(const float4*)(Xg + (size_t)grow * 64 + t * 32 + q * 8);
            const float4 v1 = *(const float4*)(Xg + (size_t)grow * 64 + t * 32 + q * 8 + 4);
            a8[0] = v0.x; a8[1] = v0.y; a8[2] = v0.z; a8[3] = v0.w;
            a8[4] = v1.x; a8[5] = v1.y; a8[6] = v1.z; a8[7] = v1.w;
        } else {
            #pragma unroll
            for (int j = 0; j < 8; ++j) a8[j] = 0.f;
        }
        short8 ah, al;
        make_hilo(a8, ah, al);
        mfma3(acc, ah, al, Bh, Bl, nkt, t0 + t, lane);
    }
}

// ---------------------------------------------------------------------------
// Weight prep (unchanged)
// ---------------------------------------------------------------------------
#define NMAT 15
struct PrepArgs {
    const float* src[NMAT];
    unsigned short* hi[NMAT];
    unsigned short* lo[NMAT];
    int nkt[NMAT];
    int KR[NMAT];
};

__global__ __launch_bounds__(256)
void prep_kernel(PrepArgs pa)
{
    const int m = blockIdx.y;
    const int nkt = pa.nkt[m];
    const int nthr = nkt * 4 * 64;
    const int p = blockIdx.x * 256 + threadIdx.x;
    if (p >= nthr) return;
    const int f = p >> 6, l = p & 63;
    const int c = f / nkt, t = f % nkt;
    const int kbase = t * 32 + ((l >> 4) << 3);
    const int n = c * 16 + (l & 15);
    const float* W = pa.src[m];
    const int KR = pa.KR[m];
    unsigned short* ph = pa.hi[m] + (size_t)p * 8;
    unsigned short* pl = pa.lo[m] + (size_t)p * 8;
    #pragma unroll
    for (int j = 0; j < 8; ++j) {
        const int k = kbase + j;
        const float v = (k < KR) ? W[k * 64 + n] : 0.f;
        const unsigned short h = f2bf(v);
        ph[j] = h;
        pl[j] = f2bf(v - bf2f(h));
    }
}

// ---------------------------------------------------------------------------
// Fused hist(+rank) / embed kernel (16 KB LDS — unchanged from R12).
// ---------------------------------------------------------------------------
struct FusedArgs {
    const int* ei; int E; int nH;
    int* h1; int* h2; unsigned int* rank;
    int tC, tV;
    const float* cf; int NC;
    const float* c_shift; const float* c_scale;
    const float* vf; int NV;
    const float* v_shift; const float* v_scale;
    const unsigned short *cW1h, *cW1l, *cW2h, *cW2l, *cWt1h, *cWt1l;
    const unsigned short *vW1h, *vW1l, *vW2h, *vW2l, *vWt1h, *vWt1l, *vWt2h, *vWt2l;
    const float *c_b1, *c_b2, *v_b1, *v_b2, *vc_bl;
    const float *vc_sf, *cv_sf;
    float* Emc; float* Emv;
    unsigned short* A1; unsigned short* B1; unsigned short* B2;
};

__global__ __launch_bounds__(256)
void fused_he_kernel(FusedArgs a)
{
    __shared__ __align__(16) float Bb[4][1024];   // Hb, then reused as Eb

    const int half = blockIdx.x & 1;
    const int idx  = blockIdx.x >> 1;

    if (half == 0) {
        const int stride = a.nH * 256;
        for (int e = idx * 256 + (int)threadIdx.x; e < a.E; e += stride) {
            const int r1 = atomicAdd(a.h1 + a.ei[e], 1);
            const int r2 = atomicAdd(a.h2 + a.ei[a.E + e], 1);
            a.rank[e] = (unsigned int)r1 | ((unsigned int)r2 << 16);
        }
        return;
    }

    int tile = idx;
    const float* x; int N; int IN;
    const float *shift, *scale, *b1, *b2, *bt1;
    const unsigned short *W1h, *W1l, *W2h, *W2l, *Wt1h, *Wt1l;
    const unsigned short *Wt2h = nullptr, *Wt2l = nullptr;
    float* Em; unsigned short* T1; unsigned short* T2 = nullptr;
    float sf1, sf2 = 0.f;
    if (tile < a.tC) {
        x = a.cf; N = a.NC; IN = 5; shift = a.c_shift; scale = a.c_scale;
        W1h = a.cW1h; W1l = a.cW1l; b1 = a.c_b1;
        W2h = a.cW2h; W2l = a.cW2l; b2 = a.c_b2;
        Em = a.Emc; Wt1h = a.cWt1h; Wt1l = a.cWt1l; bt1 = a.vc_bl;
        sf1 = a.vc_sf[0]; T1 = a.A1;
    } else {
        tile -= a.tC;
        x = a.vf; N = a.NV; IN = 19; shift = a.v_shift; scale = a.v_scale;
        W1h = a.vW1h; W1l = a.vW1l; b1 = a.v_b1;
        W2h = a.vW2h; W2l = a.vW2l; b2 = a.v_b2;
        Em = a.Emv; Wt1h = a.vWt1h; Wt1l = a.vWt1l; bt1 = nullptr;
        sf1 = a.vc_sf[0]; T1 = a.B1;
        Wt2h = a.vWt2h; Wt2l = a.vWt2l; sf2 = a.cv_sf[0]; T2 = a.B2;
    }

    const int w = threadIdx.x >> 6, lane = threadIdx.x & 63;
    const int l15 = lane & 15, q = lane >> 4;
    const int rbase = tile * 64 + w * 16;

    {
        f32x4 acc[4] = {{0,0,0,0},{0,0,0,0},{0,0,0,0},{0,0,0,0}};
        const int grow = rbase + l15;
        float a8[8];
        #pragma unroll
        for (int j = 0; j < 8; ++j) {
            const int col = q * 8 + j;
            float v = 0.f;
            if (grow < N && col < IN) v = (x[(size_t)grow * IN + col] - shift[col]) * scale[col];
            a8[j] = v;
        }
        short8 ah, al;
        make_hilo(a8, ah, al);
        mfma3(acc, ah, al, W1h, W1l, 1, 0, lane);
        #pragma unroll
        for (int c = 0; c < 4; ++c) {
            const int col = c * 16 + l15;
            const float bb = b1[col];
            #pragma unroll
            for (int r = 0; r < 4; ++r)
                Bb[w][swf(q * 4 + r, col)] = fmaxf(acc[c][r] + bb, 0.f);
        }
    }
    {
        f32x4 acc[4] = {{0,0,0,0},{0,0,0,0},{0,0,0,0},{0,0,0,0}};
        gemm_lds(acc, Bb[w], W2h, W2l, 2, 0, 2, l15, q, lane);
        #pragma unroll
        for (int c = 0; c < 4; ++c) {
            const int col = c * 16 + l15;
            const float bb = b2[col];
            #pragma unroll
            for (int r = 0; r < 4; ++r) {
                const int row = q * 4 + r;
                const int grow = rbase + row;
                const float v = fmaxf(acc[c][r] + bb, 0.f);
                Bb[w][swf(row, col)] = v;
                if (grow < N) Em[(size_t)grow * 64 + col] = v;
            }
        }
    }
    {
        f32x4 acc[4] = {{0,0,0,0},{0,0,0,0},{0,0,0,0},{0,0,0,0}};
        gemm_lds(acc, Bb[w], Wt1h, Wt1l, 2, 0, 2, l15, q, lane);
        #pragma unroll
        for (int c = 0; c < 4; ++c) {
            const int col = c * 16 + l15;
            const float bb = bt1 ? bt1[col] : 0.f;
            #pragma unroll
            for (int r = 0; r < 4; ++r) {
                const int grow = rbase + q * 4 + r;
                if (grow < N) T1[(size_t)grow * 64 + col] = f2bf(sf1 * (acc[c][r] + bb));
            }
        }
    }
    if (T2 != nullptr) {
        f32x4 acc[4] = {{0,0,0,0},{0,0,0,0},{0,0,0,0},{0,0,0,0}};
        gemm_lds(acc, Bb[w], Wt2h, Wt2l, 2, 0, 2, l15, q, lane);
        #pragma unroll
        for (int c = 0; c < 4; ++c) {
            const int col = c * 16 + l15;
            #pragma unroll
            for (int r = 0; r < 4; ++r) {
                const int grow = rbase + q * 4 + r;
                if (grow < N) T2[(size_t)grow * 64 + col] = f2bf(sf2 * acc[c][r]);
            }
        }
    }
}

// ---------------------------------------------------------------------------
// Post-conv (unchanged from R12)
// ---------------------------------------------------------------------------
template<bool IS_POST2>
__global__ __launch_bounds__(256)
void post_mfma(int N, const float* __restrict__ G, const int* __restrict__ rs,
               const float* __restrict__ Em,
               const unsigned short* __restrict__ Wfh, const unsigned short* __restrict__ Wfl,
               const float* __restrict__ bfv, const float* __restrict__ spp,
               const unsigned short* __restrict__ Woah, const unsigned short* __restrict__ Woal,
               const float* __restrict__ boa,
               const unsigned short* __restrict__ Wobh, const unsigned short* __restrict__ Wobl,
               const float* __restrict__ bob,
               const unsigned short* __restrict__ W4h, const unsigned short* __restrict__ W4l,
               const float* __restrict__ b4,
               const float* __restrict__ sf2p, unsigned short* __restrict__ A2,
               const float* __restrict__ oW2, float* __restrict__ out)
{
    __shared__ __align__(16) float BA[4][1024];
    __shared__ __align__(16) float BB[4][1024];

    const int w = threadIdx.x >> 6, lane = threadIdx.x & 63;
    const int l15 = lane & 15, q = lane >> 4;
    const float sp = spp[0];
    const float sf2 = IS_POST2 ? 0.f : sf2p[0];
    const int rbase = blockIdx.x * 64 + w * 16;

    {
        f32x4 acc[4] = {{0,0,0,0},{0,0,0,0},{0,0,0,0},{0,0,0,0}};
        gemm_glb(acc, G, rbase, N, Wfh, Wfl, 2, 0, 2, l15, q, lane);
        float dgr[4];
        #pragma unroll
        for (int r = 0; r < 4; ++r) {
            const int grow = rbase + q * 4 + r;
            dgr[r] = (grow < N) ? (float)(rs[grow + 1] - rs[grow]) : 0.f;
        }
        #pragma unroll
        for (int c = 0; c < 4; ++c) {
            const int col = c * 16 + l15;
            const float bb = bfv[col];
            #pragma unroll
            for (int r = 0; r < 4; ++r)
                BA[w][swf(q * 4 + r, col)] = (acc[c][r] + dgr[r] * bb) * sp;
        }
    }
    {
        f32x4 acc[4] = {{0,0,0,0},{0,0,0,0},{0,0,0,0},{0,0,0,0}};
        gemm_lds(acc, BA[w], Woah, Woal, 4, 0, 2, l15, q, lane);
        gemm_glb(acc, Em, rbase, N, Woah, Woal, 4, 2, 2, l15, q, lane);
        #pragma unroll
        for (int c = 0; c < 4; ++c) {
            const int col = c * 16 + l15;
            const float bb = boa[col];
            #pragma unroll
            for (int r = 0; r < 4; ++r)
                BB[w][swf(q * 4 + r, col)] = fmaxf(acc[c][r] + bb, 0.f);
        }
    }
    {
        f32x4 acc[4] = {{0,0,0,0},{0,0,0,0},{0,0,0,0},{0,0,0,0}};
        gemm_lds(acc, BB[w], Wobh, Wobl, 2, 0, 2, l15, q, lane);
        #pragma unroll
        for (int c = 0; c < 4; ++c) {
            const int col = c * 16 + l15;
            const float bb = bob[col];
            #pragma unroll
            for (int r = 0; r < 4; ++r)
                BA[w][swf(q * 4 + r, col)] = fmaxf(acc[c][r] + bb, 0.f);
        }
    }
    {
        f32x4 acc[4] = {{0,0,0,0},{0,0,0,0},{0,0,0,0},{0,0,0,0}};
        gemm_lds(acc, BA[w], W4h, W4l, 2, 0, 2, l15, q, lane);
        if (!IS_POST2) {
            #pragma unroll
            for (int c = 0; c < 4; ++c) {
                const int col = c * 16 + l15;
                const float bb = b4[col];
                #pragma unroll
                for (int r = 0; r < 4; ++r) {
                    const int grow = rbase + q * 4 + r;
                    if (grow < N) A2[(size_t)grow * 64 + col] = f2bf(sf2 * (acc[c][r] + bb));
                }
            }
        } else {
            float w2c[4], bb4[4];
            #pragma unroll
            for (int c = 0; c < 4; ++c) {
                const int col = c * 16 + l15;
                w2c[c] = oW2[col];
                bb4[c] = b4[col];
            }
            #pragma unroll
            for (int r = 0; r < 4; ++r) {
                float s = 0.f;
                #pragma unroll
                for (int c = 0; c < 4; ++c)
                    s += fmaxf(acc[c][r] + bb4[c], 0.f) * w2c[c];
                s += __shfl_xor(s, 1);
                s += __shfl_xor(s, 2);
                s += __shfl_xor(s, 4);
                s += __shfl_xor(s, 8);
                const int grow = rbase + q * 4 + r;
                if (l15 == 0 && grow < N) out[grow] = s;
            }
        }
    }
}

// ---------------------------------------------------------------------------
// Multiblock scans (unchanged from R12)
// ---------------------------------------------------------------------------
__global__ __launch_bounds__(256)
void scanA2_kernel(const int* __restrict__ h1, int n1, int* __restrict__ cs1,
                   const int* __restrict__ h2, int n2, int* __restrict__ cs2)
{
    __shared__ int wsum[4];
    const int which = blockIdx.y;
    const int* h = which ? h2 : h1;
    const int n = which ? n2 : n1;
    int* csum = which ? cs2 : cs1;
    if (blockIdx.x * 4096 >= n) return;

    const int t = threadIdx.x, lane = t & 63, wid = t >> 6;
    const int base = blockIdx.x * 4096 + t * 16;
    int s = 0;
    #pragma unroll
    for (int j = 0; j < 16; ++j) {
        const int idx = base + j;
        if (idx < n) s += h[idx];
    }
    #pragma unroll
    for (int d = 1; d < 64; d <<= 1) s += __shfl_xor(s, d);
    if (lane == 0) wsum[wid] = s;
    __syncthreads();
    if (t == 0) csum[blockIdx.x] = wsum[0] + wsum[1] + wsum[2] + wsum[3];
}

__global__ __launch_bounds__(256)
void scanB2_kernel(int* __restrict__ cs1, int nch1, int* __restrict__ rs1, int n1,
                   int* __restrict__ cs2, int nch2, int* __restrict__ rs2, int n2)
{
    __shared__ int wsum[4];
    const int which = blockIdx.x;
    int* csum = which ? cs2 : cs1;
    const int nchunks = which ? nch2 : nch1;
    int* rs = which ? rs2 : rs1;
    const int n = which ? n2 : n1;

    const int t = threadIdx.x, lane = t & 63, wid = t >> 6;
    const int v = (t < nchunks) ? csum[t] : 0;
    int x = v;
    #pragma unroll
    for (int d = 1; d < 64; d <<= 1) { int y = __shfl_up(x, d); if (lane >= d) x += y; }
    if (lane == 63) wsum[wid] = x;
    __syncthreads();
    int woff = 0;
    for (int i = 0; i < wid; ++i) woff += wsum[i];
    if (t < nchunks) csum[t] = woff + x - v;
    if (t == 0) rs[n] = wsum[0] + wsum[1] + wsum[2] + wsum[3];
}

__global__ __launch_bounds__(256)
void scanC2_kernel(const int* __restrict__ h1, int n1, const int* __restrict__ cs1,
                   int* __restrict__ rs1,
                   const int* __restrict__ h2, int n2, const int* __restrict__ cs2,
                   int* __restrict__ rs2)
{
    __shared__ int wsum[4];
    const int which = blockIdx.y;
    const int* h = which ? h2 : h1;
    const int n = which ? n2 : n1;
    const int* csum = which ? cs2 : cs1;
    int* rs = which ? rs2 : rs1;
    if (blockIdx.x * 4096 >= n) return;

    const int t = threadIdx.x, lane = t & 63, wid = t >> 6;
    const int base = blockIdx.x * 4096 + t * 16;
    int loc[16];
    int s = 0;
    #pragma unroll
    for (int j = 0; j < 16; ++j) {
        loc[j] = s;
        const int idx = base + j;
        if (idx < n) s += h[idx];
    }
    int x = s;
    #pragma unroll
    for (int d = 1; d < 64; d <<= 1) { int y = __shfl_up(x, d); if (lane >= d) x += y; }
    if (lane == 63) wsum[wid] = x;
    __syncthreads();
    int woff = 0;
    for (int i = 0; i < wid; ++i) woff += wsum[i];
    const int toff = csum[blockIdx.x] + woff + x - s;
    #pragma unroll
    for (int j = 0; j < 16; ++j) {
        const int idx = base + j;
        if (idx < n) rs[idx] = toff + loc[j];
    }
}

// ---------------------------------------------------------------------------
// Atomic-free single-pass scatter with non-temporal 8B stores.
// ---------------------------------------------------------------------------
__global__ __launch_bounds__(256)
void scatter_kernel(const int* __restrict__ ei, int E,
                    const float* __restrict__ ef,
                    const float* __restrict__ eshp, const float* __restrict__ escp,
                    const unsigned int* __restrict__ rank,
                    const int* __restrict__ rs1, const int* __restrict__ rs2,
                    long long* __restrict__ pairs1, long long* __restrict__ pairs2)
{
    const int e = blockIdx.x * 256 + threadIdx.x;
    if (e >= E) return;
    const int i0 = ei[e];
    const int i1 = ei[E + e];
    const unsigned int rk = rank[e];
    const float en = (ef[e] - eshp[0]) * escp[0];
    const unsigned long long enb = (unsigned long long)(unsigned int)__float_as_int(en) << 32;
    const int pos1 = rs1[i0] + (int)(rk & 0xffffu);
    const int pos2 = rs2[i1] + (int)(rk >> 16);
    // layout matches int2{src, en}: low 32 = src, high 32 = en bits (LE)
    __builtin_nontemporal_store((long long)(enb | (unsigned int)i1), pairs1 + pos1);
    __builtin_nontemporal_store((long long)(enb | (unsigned int)i0), pairs2 + pos2);
}

// ---------------------------------------------------------------------------
// Gather-aggregate, 8-way unrolled (8 outstanding row-gathers per wave,
// one row per wave -> full 200K-wave concurrency preserved).
// ---------------------------------------------------------------------------
DEV void agg_body(int row, int j, const int* __restrict__ rs,
                  const int2* __restrict__ pairs,
                  const unsigned short* __restrict__ Ttgt,
                  const unsigned short* __restrict__ Tsrc,
                  const float* __restrict__ We, const float* __restrict__ sfp,
                  float* __restrict__ G)
{
    const float base = bf2f(Ttgt[(size_t)row * 64 + j]);
    const float sfWe = sfp[0] * We[j];
    const int s = rs[row];
    const int e = rs[row + 1];
    float acc = 0.f;
    int p = s;
    for (; p + 7 < e; p += 8) {
        int2 a[8];
        float b[8];
        #pragma unroll
        for (int u = 0; u < 8; ++u) a[u] = pairs[p + u];
        #pragma unroll
        for (int u = 0; u < 8; ++u) b[u] = bf2f(Tsrc[(size_t)a[u].x * 64 + j]);
        #pragma unroll
        for (int u = 0; u < 8; ++u)
            acc += fmaxf(base + b[u] + __int_as_float(a[u].y) * sfWe, 0.f);
    }
    for (; p < e; ++p) {
        const int2 pr = pairs[p];
        const float bs = bf2f(Tsrc[(size_t)pr.x * 64 + j]);
        acc += fmaxf(base + bs + __int_as_float(pr.y) * sfWe, 0.f);
    }
    G[(size_t)row * 64 + j] = acc;
}

__global__ __launch_bounds__(256)
void agg_kernel(int nrows, const int* __restrict__ rs,
                const int2* __restrict__ pairs,
                const unsigned short* __restrict__ Ttgt,
                const unsigned short* __restrict__ Tsrc,
                const float* __restrict__ We, const float* __restrict__ sfp,
                float* __restrict__ G)
{
    const int row = blockIdx.x * 4 + (int)(threadIdx.x >> 6);
    if (row >= nrows) return;
    agg_body(row, (int)(threadIdx.x & 63), rs, pairs, Ttgt, Tsrc, We, sfp, G);
}

// ---------------------------------------------------------------------------
extern "C" void kernel_launch(void* const* d_in, const int* in_sizes, int n_in,
                              void* d_out, int out_size, void* d_ws, size_t ws_size,
                              hipStream_t stream)
{
    const float* cf      = (const float*)d_in[0];
    const float* ef      = (const float*)d_in[1];
    const float* vf      = (const float*)d_in[2];
    const float* c_shift = (const float*)d_in[3];
    const float* c_scale = (const float*)d_in[4];
    const float* v_shift = (const float*)d_in[5];
    const float* v_scale = (const float*)d_in[6];
    const float* e_shift = (const float*)d_in[7];
    const float* e_scale = (const float*)d_in[8];
    const float* c_W1 = (const float*)d_in[9];
    const float* c_b1 = (const float*)d_in[10];
    const float* c_W2 = (const float*)d_in[11];
    const float* c_b2 = (const float*)d_in[12];
    const float* v_W1 = (const float*)d_in[13];
    const float* v_b1 = (const float*)d_in[14];
    const float* v_W2 = (const float*)d_in[15];
    const float* v_b2 = (const float*)d_in[16];
    const float* vc_Wl  = (const float*)d_in[17];
    const float* vc_bl  = (const float*)d_in[18];
    const float* vc_We  = (const float*)d_in[19];
    const float* vc_Wr  = (const float*)d_in[20];
    const float* vc_sf  = (const float*)d_in[21];
    const float* vc_Wf  = (const float*)d_in[22];
    const float* vc_bf  = (const float*)d_in[23];
    const float* vc_sp  = (const float*)d_in[24];
    const float* vc_Woa = (const float*)d_in[25];
    const float* vc_boa = (const float*)d_in[26];
    const float* vc_Wob = (const float*)d_in[27];
    const float* vc_bob = (const float*)d_in[28];
    const float* cv_Wl  = (const float*)d_in[29];
    const float* cv_bl  = (const float*)d_in[30];
    const float* cv_We  = (const float*)d_in[31];
    const float* cv_Wr  = (const float*)d_in[32];
    const float* cv_sf  = (const float*)d_in[33];
    const float* cv_Wf  = (const float*)d_in[34];
    const float* cv_bf  = (const float*)d_in[35];
    const float* cv_sp  = (const float*)d_in[36];
    const float* cv_Woa = (const float*)d_in[37];
    const float* cv_boa = (const float*)d_in[38];
    const float* cv_Wob = (const float*)d_in[39];
    const float* cv_bob = (const float*)d_in[40];
    const float* out_W1 = (const float*)d_in[41];
    const float* out_b1 = (const float*)d_in[42];
    const float* out_W2 = (const float*)d_in[43];
    const int*   eidx   = (const int*)d_in[44];

    const int NC = in_sizes[0] / 5;
    const int NV = in_sizes[2] / 19;
    const int E  = in_sizes[1];

    // ---- workspace layout (256B aligned slots) ----
    // ws budget ~256MB: rank aliases G2's slot (rank written by fused hist,
    // last read by scatter; G2 first written by agg2, strictly after).
    char* ws = (char*)d_ws;
    size_t off = 0;
    auto alloc = [&](size_t bytes) -> size_t {
        size_t o = off;
        off = (off + bytes + 255) & ~(size_t)255;
        return o;
    };
    size_t o_h1 = alloc((size_t)NC * 4);
    size_t o_h2 = alloc((size_t)NV * 4);
    size_t zero_bytes = off;
    size_t o_rs1  = alloc((size_t)(NC + 1) * 4);
    size_t o_rs2  = alloc((size_t)(NV + 1) * 4);
    size_t o_cs1  = alloc(256 * 4);
    size_t o_cs2  = alloc(256 * 4);
    size_t o_p1   = alloc((size_t)E * 8);
    size_t o_p2   = alloc((size_t)E * 8);
    size_t o_G1   = alloc((size_t)NC * 64 * 4);
    size_t o_G2   = alloc((size_t)NV * 64 * 4);  // also hosts rank[E] (u32) early
    size_t o_Emc  = alloc((size_t)NC * 64 * 4);
    size_t o_Emv  = alloc((size_t)NV * 64 * 4);
    size_t o_A1   = alloc((size_t)NC * 64 * 2);  // A2 aliases A1 (dead after agg1)
    size_t o_B1   = alloc((size_t)NV * 64 * 2);
    size_t o_B2   = alloc((size_t)NV * 64 * 2);

    static const int nkt_arr[NMAT] = {1,2,2,1,2,2,2,2,4,2,2,2,4,2,2};
    static const int KR_arr[NMAT]  = {5,64,64,19,64,64,64,64,128,64,64,64,128,64,64};
    const float* src_arr[NMAT] = {c_W1, c_W2, vc_Wl, v_W1, v_W2, vc_Wr, cv_Wr,
                                  vc_Wf, vc_Woa, vc_Wob, cv_Wl,
                                  cv_Wf, cv_Woa, cv_Wob, out_W1};
    size_t o_wh[NMAT], o_wl[NMAT];
    for (int m = 0; m < NMAT; ++m) {
        o_wh[m] = alloc((size_t)nkt_arr[m] * 4 * 64 * 8 * 2);
        o_wl[m] = alloc((size_t)nkt_arr[m] * 4 * 64 * 8 * 2);
    }
    (void)ws_size; (void)n_in; (void)out_size;

    int*  h1   = (int*)(ws + o_h1);
    int*  h2   = (int*)(ws + o_h2);
    int*  rs1  = (int*)(ws + o_rs1);
    int*  rs2  = (int*)(ws + o_rs2);
    int*  cs1  = (int*)(ws + o_cs1);
    int*  cs2  = (int*)(ws + o_cs2);
    unsigned int* rank = (unsigned int*)(ws + o_G2);   // alias: E*4 <= NV*256
    int2* p1   = (int2*)(ws + o_p1);
    int2* p2   = (int2*)(ws + o_p2);
    float* G1  = (float*)(ws + o_G1);
    float* G2  = (float*)(ws + o_G2);
    float* Emc = (float*)(ws + o_Emc);
    float* Emv = (float*)(ws + o_Emv);
    unsigned short* A1 = (unsigned short*)(ws + o_A1);
    unsigned short* B1 = (unsigned short*)(ws + o_B1);
    unsigned short* A2 = (unsigned short*)(ws + o_A1);  // alias
    unsigned short* B2 = (unsigned short*)(ws + o_B2);

    PrepArgs pa;
    for (int m = 0; m < NMAT; ++m) {
        pa.src[m] = src_arr[m];
        pa.hi[m] = (unsigned short*)(ws + o_wh[m]);
        pa.lo[m] = (unsigned short*)(ws + o_wl[m]);
        pa.nkt[m] = nkt_arr[m];
        pa.KR[m] = KR_arr[m];
    }
    auto WH = [&](int m) { return (const unsigned short*)(ws + o_wh[m]); };
    auto WL = [&](int m) { return (const unsigned short*)(ws + o_wl[m]); };

    hipMemsetAsync(ws, 0, zero_bytes, stream);

    // --- weight prep ---
    prep_kernel<<<dim3(4, NMAT), 256, 0, stream>>>(pa);

    // --- fused histogram(+rank) / embeddings ---
    const int tC = (NC + 63) >> 6, tV = (NV + 63) >> 6;
    const int nE = tC + tV;
    FusedArgs fa;
    fa.ei = eidx; fa.E = E; fa.nH = nE;
    fa.h1 = h1; fa.h2 = h2; fa.rank = rank;
    fa.tC = tC; fa.tV = tV;
    fa.cf = cf; fa.NC = NC; fa.c_shift = c_shift; fa.c_scale = c_scale;
    fa.vf = vf; fa.NV = NV; fa.v_shift = v_shift; fa.v_scale = v_scale;
    fa.cW1h = WH(0); fa.cW1l = WL(0); fa.cW2h = WH(1); fa.cW2l = WL(1);
    fa.cWt1h = WH(2); fa.cWt1l = WL(2);
    fa.vW1h = WH(3); fa.vW1l = WL(3); fa.vW2h = WH(4); fa.vW2l = WL(4);
    fa.vWt1h = WH(5); fa.vWt1l = WL(5); fa.vWt2h = WH(6); fa.vWt2l = WL(6);
    fa.c_b1 = c_b1; fa.c_b2 = c_b2; fa.v_b1 = v_b1; fa.v_b2 = v_b2;
    fa.vc_bl = vc_bl; fa.vc_sf = vc_sf; fa.cv_sf = cv_sf;
    fa.Emc = Emc; fa.Emv = Emv; fa.A1 = A1; fa.B1 = B1; fa.B2 = B2;
    fused_he_kernel<<<2 * nE, 256, 0, stream>>>(fa);

    // --- fused scans ---
    const int nch1 = (NC + 4095) / 4096, nch2 = (NV + 4095) / 4096;
    const int nchm = nch1 > nch2 ? nch1 : nch2;
    scanA2_kernel<<<dim3(nchm, 2), 256, 0, stream>>>(h1, NC, cs1, h2, NV, cs2);
    scanB2_kernel<<<2, 256, 0, stream>>>(cs1, nch1, rs1, NC, cs2, nch2, rs2, NV);
    scanC2_kernel<<<dim3(nchm, 2), 256, 0, stream>>>(h1, NC, cs1, rs1, h2, NV, cs2, rs2);

    // --- atomic-free single-pass scatter (nt stores) ---
    scatter_kernel<<<(E + 255) / 256, 256, 0, stream>>>(
        eidx, E, ef, e_shift, e_scale, rank, rs1, rs2,
        (long long*)p1, (long long*)p2);
    // rank (G2 slot) dead from here; agg2 overwrites G2 below.

    // --- conv1: target ei0 -> Ttgt=A1, Tsrc=B1 ---
    agg_kernel<<<(NC + 3) / 4, 256, 0, stream>>>(
        NC, rs1, p1, A1, B1, vc_We, vc_sf, G1);
    post_mfma<false><<<tC, 256, 0, stream>>>(
        NC, G1, rs1, Emc,
        WH(7), WL(7), vc_bf, vc_sp,
        WH(8), WL(8), vc_boa,
        WH(9), WL(9), vc_bob,
        WH(10), WL(10), cv_bl,
        cv_sf, A2, nullptr, nullptr);

    // --- conv2: target ei1 -> Ttgt=B2, Tsrc=A2 ---
    agg_kernel<<<(NV + 3) / 4, 256, 0, stream>>>(
        NV, rs2, p2, B2, A2, cv_We, cv_sf, G2);
    post_mfma<true><<<tV, 256, 0, stream>>>(
        NV, G2, rs2, Emv,
        WH(11), WL(11), cv_bf, cv_sp,
        WH(12), WL(12), cv_boa,
        WH(13), WL(13), cv_bob,
        WH(14), WL(14), out_b1,
        nullptr, nullptr, out_W2, (float*)d_out);
}

// Round 15
// 712.246 us; speedup vs baseline: 1.1736x; 1.1060x over previous
//
#include <hip/hip_runtime.h>
#include <hip/hip_bf16.h>

#define DEV __device__ __forceinline__

typedef __attribute__((ext_vector_type(8))) short short8;
typedef __attribute__((ext_vector_type(4))) float f32x4;

DEV unsigned short f2bf(float f) {
    __hip_bfloat16 h = __float2bfloat16(f);
    unsigned short u;
    __builtin_memcpy(&u, &h, 2);
    return u;
}
DEV float bf2f(unsigned short u) { return __uint_as_float((unsigned int)u << 16); }

DEV f32x4 mfma_bf16(short8 a, short8 b, f32x4 c) {
    return __builtin_amdgcn_mfma_f32_16x16x32_bf16(a, b, c, 0, 0, 0);
}

// fp32 -> (hi, lo) bf16 pair; hi+lo represents v to ~2^-17 rel.
DEV void make_hilo(const float* a8, short8& hi, short8& lo) {
    #pragma unroll
    for (int j = 0; j < 8; ++j) {
        const float v = a8[j];
        const unsigned short h = f2bf(v);
        hi[j] = (short)h;
        lo[j] = (short)f2bf(v - bf2f(h));
    }
}

// 3-term split-precision MFMA accumulate against 4 column-frags.
DEV void mfma3(f32x4 acc[4], short8 ah, short8 al,
               const unsigned short* __restrict__ Bh,
               const unsigned short* __restrict__ Bl,
               int nkt, int tidx, int lane) {
    #pragma unroll
    for (int c = 0; c < 4; ++c) {
        const size_t o = ((size_t)(c * nkt + tidx) * 64 + lane) * 8;
        const short8 bh = *(const short8*)(Bh + o);
        const short8 bl = *(const short8*)(Bl + o);
        acc[c] = mfma_bf16(ah, bh, acc[c]);
        acc[c] = mfma_bf16(al, bh, acc[c]);
        acc[c] = mfma_bf16(ah, bl, acc[c]);
    }
}

// XOR-chunk-swizzled fp32 activation buffer (16 rows x 64)
DEV int swf(int row, int col) {
    return row * 64 + ((((col >> 3) ^ row) & 7) << 3) + (col & 7);
}

DEV void gemm_lds(f32x4 acc[4], const float* Xl,
                  const unsigned short* Bh, const unsigned short* Bl,
                  int nkt, int t0, int ntk, int l15, int q, int lane) {
    for (int t = 0; t < ntk; ++t) {
        const int ch = (t * 4 + q) ^ (l15 & 7);
        const float* a8 = Xl + l15 * 64 + ch * 8;
        short8 ah, al;
        make_hilo(a8, ah, al);
        mfma3(acc, ah, al, Bh, Bl, nkt, t0 + t, lane);
    }
}

DEV void gemm_glb(f32x4 acc[4], const float* __restrict__ Xg, int rbase, int N,
                  const unsigned short* Bh, const unsigned short* Bl,
                  int nkt, int t0, int ntk, int l15, int q, int lane) {
    const int grow = rbase + l15;
    const bool ok = grow < N;
    for (int t = 0; t < ntk; ++t) {
        float a8[8];
        if (ok) {
            const float4 v0 = *(const float4*)(Xg + (size_t)grow * 64 + t * 32 + q * 8);
            const float4 v1 = *(const float4*)(Xg + (size_t)grow * 64 + t * 32 + q * 8 + 4);
            a8[0] = v0.x; a8[1] = v0.y; a8[2] = v0.z; a8[3] = v0.w;
            a8[4] = v1.x; a8[5] = v1.y; a8[6] = v1.z; a8[7] = v1.w;
        } else {
            #pragma unroll
            for (int j = 0; j < 8; ++j) a8[j] = 0.f;
        }
        short8 ah, al;
        make_hilo(a8, ah, al);
        mfma3(acc, ah, al, Bh, Bl, nkt, t0 + t, lane);
    }
}

// ---------------------------------------------------------------------------
// Weight prep (unchanged)
// ---------------------------------------------------------------------------
#define NMAT 15
struct PrepArgs {
    const float* src[NMAT];
    unsigned short* hi[NMAT];
    unsigned short* lo[NMAT];
    int nkt[NMAT];
    int KR[NMAT];
};

__global__ __launch_bounds__(256)
void prep_kernel(PrepArgs pa)
{
    const int m = blockIdx.y;
    const int nkt = pa.nkt[m];
    const int nthr = nkt * 4 * 64;
    const int p = blockIdx.x * 256 + threadIdx.x;
    if (p >= nthr) return;
    const int f = p >> 6, l = p & 63;
    const int c = f / nkt, t = f % nkt;
    const int kbase = t * 32 + ((l >> 4) << 3);
    const int n = c * 16 + (l & 15);
    const float* W = pa.src[m];
    const int KR = pa.KR[m];
    unsigned short* ph = pa.hi[m] + (size_t)p * 8;
    unsigned short* pl = pa.lo[m] + (size_t)p * 8;
    #pragma unroll
    for (int j = 0; j < 8; ++j) {
        const int k = kbase + j;
        const float v = (k < KR) ? W[k * 64 + n] : 0.f;
        const unsigned short h = f2bf(v);
        ph[j] = h;
        pl[j] = f2bf(v - bf2f(h));
    }
}

// ---------------------------------------------------------------------------
// Fused hist(+rank) / embed kernel (16 KB LDS — unchanged from R12).
// ---------------------------------------------------------------------------
struct FusedArgs {
    const int* ei; int E; int nH;
    int* h1; int* h2; unsigned int* rank;
    int tC, tV;
    const float* cf; int NC;
    const float* c_shift; const float* c_scale;
    const float* vf; int NV;
    const float* v_shift; const float* v_scale;
    const unsigned short *cW1h, *cW1l, *cW2h, *cW2l, *cWt1h, *cWt1l;
    const unsigned short *vW1h, *vW1l, *vW2h, *vW2l, *vWt1h, *vWt1l, *vWt2h, *vWt2l;
    const float *c_b1, *c_b2, *v_b1, *v_b2, *vc_bl;
    const float *vc_sf, *cv_sf;
    float* Emc; float* Emv;
    unsigned short* A1; unsigned short* B1; unsigned short* B2;
};

__global__ __launch_bounds__(256)
void fused_he_kernel(FusedArgs a)
{
    __shared__ __align__(16) float Bb[4][1024];   // Hb, then reused as Eb

    const int half = blockIdx.x & 1;
    const int idx  = blockIdx.x >> 1;

    if (half == 0) {
        const int stride = a.nH * 256;
        for (int e = idx * 256 + (int)threadIdx.x; e < a.E; e += stride) {
            const int r1 = atomicAdd(a.h1 + a.ei[e], 1);
            const int r2 = atomicAdd(a.h2 + a.ei[a.E + e], 1);
            a.rank[e] = (unsigned int)r1 | ((unsigned int)r2 << 16);
        }
        return;
    }

    int tile = idx;
    const float* x; int N; int IN;
    const float *shift, *scale, *b1, *b2, *bt1;
    const unsigned short *W1h, *W1l, *W2h, *W2l, *Wt1h, *Wt1l;
    const unsigned short *Wt2h = nullptr, *Wt2l = nullptr;
    float* Em; unsigned short* T1; unsigned short* T2 = nullptr;
    float sf1, sf2 = 0.f;
    if (tile < a.tC) {
        x = a.cf; N = a.NC; IN = 5; shift = a.c_shift; scale = a.c_scale;
        W1h = a.cW1h; W1l = a.cW1l; b1 = a.c_b1;
        W2h = a.cW2h; W2l = a.cW2l; b2 = a.c_b2;
        Em = a.Emc; Wt1h = a.cWt1h; Wt1l = a.cWt1l; bt1 = a.vc_bl;
        sf1 = a.vc_sf[0]; T1 = a.A1;
    } else {
        tile -= a.tC;
        x = a.vf; N = a.NV; IN = 19; shift = a.v_shift; scale = a.v_scale;
        W1h = a.vW1h; W1l = a.vW1l; b1 = a.v_b1;
        W2h = a.vW2h; W2l = a.vW2l; b2 = a.v_b2;
        Em = a.Emv; Wt1h = a.vWt1h; Wt1l = a.vWt1l; bt1 = nullptr;
        sf1 = a.vc_sf[0]; T1 = a.B1;
        Wt2h = a.vWt2h; Wt2l = a.vWt2l; sf2 = a.cv_sf[0]; T2 = a.B2;
    }

    const int w = threadIdx.x >> 6, lane = threadIdx.x & 63;
    const int l15 = lane & 15, q = lane >> 4;
    const int rbase = tile * 64 + w * 16;

    {
        f32x4 acc[4] = {{0,0,0,0},{0,0,0,0},{0,0,0,0},{0,0,0,0}};
        const int grow = rbase + l15;
        float a8[8];
        #pragma unroll
        for (int j = 0; j < 8; ++j) {
            const int col = q * 8 + j;
            float v = 0.f;
            if (grow < N && col < IN) v = (x[(size_t)grow * IN + col] - shift[col]) * scale[col];
            a8[j] = v;
        }
        short8 ah, al;
        make_hilo(a8, ah, al);
        mfma3(acc, ah, al, W1h, W1l, 1, 0, lane);
        #pragma unroll
        for (int c = 0; c < 4; ++c) {
            const int col = c * 16 + l15;
            const float bb = b1[col];
            #pragma unroll
            for (int r = 0; r < 4; ++r)
                Bb[w][swf(q * 4 + r, col)] = fmaxf(acc[c][r] + bb, 0.f);
        }
    }
    {
        f32x4 acc[4] = {{0,0,0,0},{0,0,0,0},{0,0,0,0},{0,0,0,0}};
        gemm_lds(acc, Bb[w], W2h, W2l, 2, 0, 2, l15, q, lane);
        #pragma unroll
        for (int c = 0; c < 4; ++c) {
            const int col = c * 16 + l15;
            const float bb = b2[col];
            #pragma unroll
            for (int r = 0; r < 4; ++r) {
                const int row = q * 4 + r;
                const int grow = rbase + row;
                const float v = fmaxf(acc[c][r] + bb, 0.f);
                Bb[w][swf(row, col)] = v;
                if (grow < N) Em[(size_t)grow * 64 + col] = v;
            }
        }
    }
    {
        f32x4 acc[4] = {{0,0,0,0},{0,0,0,0},{0,0,0,0},{0,0,0,0}};
        gemm_lds(acc, Bb[w], Wt1h, Wt1l, 2, 0, 2, l15, q, lane);
        #pragma unroll
        for (int c = 0; c < 4; ++c) {
            const int col = c * 16 + l15;
            const float bb = bt1 ? bt1[col] : 0.f;
            #pragma unroll
            for (int r = 0; r < 4; ++r) {
                const int grow = rbase + q * 4 + r;
                if (grow < N) T1[(size_t)grow * 64 + col] = f2bf(sf1 * (acc[c][r] + bb));
            }
        }
    }
    if (T2 != nullptr) {
        f32x4 acc[4] = {{0,0,0,0},{0,0,0,0},{0,0,0,0},{0,0,0,0}};
        gemm_lds(acc, Bb[w], Wt2h, Wt2l, 2, 0, 2, l15, q, lane);
        #pragma unroll
        for (int c = 0; c < 4; ++c) {
            const int col = c * 16 + l15;
            #pragma unroll
            for (int r = 0; r < 4; ++r) {
                const int grow = rbase + q * 4 + r;
                if (grow < N) T2[(size_t)grow * 64 + col] = f2bf(sf2 * acc[c][r]);
            }
        }
    }
}

// ---------------------------------------------------------------------------
// Post-conv (unchanged from R12)
// ---------------------------------------------------------------------------
template<bool IS_POST2>
__global__ __launch_bounds__(256)
void post_mfma(int N, const float* __restrict__ G, const int* __restrict__ rs,
               const float* __restrict__ Em,
               const unsigned short* __restrict__ Wfh, const unsigned short* __restrict__ Wfl,
               const float* __restrict__ bfv, const float* __restrict__ spp,
               const unsigned short* __restrict__ Woah, const unsigned short* __restrict__ Woal,
               const float* __restrict__ boa,
               const unsigned short* __restrict__ Wobh, const unsigned short* __restrict__ Wobl,
               const float* __restrict__ bob,
               const unsigned short* __restrict__ W4h, const unsigned short* __restrict__ W4l,
               const float* __restrict__ b4,
               const float* __restrict__ sf2p, unsigned short* __restrict__ A2,
               const float* __restrict__ oW2, float* __restrict__ out)
{
    __shared__ __align__(16) float BA[4][1024];
    __shared__ __align__(16) float BB[4][1024];

    const int w = threadIdx.x >> 6, lane = threadIdx.x & 63;
    const int l15 = lane & 15, q = lane >> 4;
    const float sp = spp[0];
    const float sf2 = IS_POST2 ? 0.f : sf2p[0];
    const int rbase = blockIdx.x * 64 + w * 16;

    {
        f32x4 acc[4] = {{0,0,0,0},{0,0,0,0},{0,0,0,0},{0,0,0,0}};
        gemm_glb(acc, G, rbase, N, Wfh, Wfl, 2, 0, 2, l15, q, lane);
        float dgr[4];
        #pragma unroll
        for (int r = 0; r < 4; ++r) {
            const int grow = rbase + q * 4 + r;
            dgr[r] = (grow < N) ? (float)(rs[grow + 1] - rs[grow]) : 0.f;
        }
        #pragma unroll
        for (int c = 0; c < 4; ++c) {
            const int col = c * 16 + l15;
            const float bb = bfv[col];
            #pragma unroll
            for (int r = 0; r < 4; ++r)
                BA[w][swf(q * 4 + r, col)] = (acc[c][r] + dgr[r] * bb) * sp;
        }
    }
    {
        f32x4 acc[4] = {{0,0,0,0},{0,0,0,0},{0,0,0,0},{0,0,0,0}};
        gemm_lds(acc, BA[w], Woah, Woal, 4, 0, 2, l15, q, lane);
        gemm_glb(acc, Em, rbase, N, Woah, Woal, 4, 2, 2, l15, q, lane);
        #pragma unroll
        for (int c = 0; c < 4; ++c) {
            const int col = c * 16 + l15;
            const float bb = boa[col];
            #pragma unroll
            for (int r = 0; r < 4; ++r)
                BB[w][swf(q * 4 + r, col)] = fmaxf(acc[c][r] + bb, 0.f);
        }
    }
    {
        f32x4 acc[4] = {{0,0,0,0},{0,0,0,0},{0,0,0,0},{0,0,0,0}};
        gemm_lds(acc, BB[w], Wobh, Wobl, 2, 0, 2, l15, q, lane);
        #pragma unroll
        for (int c = 0; c < 4; ++c) {
            const int col = c * 16 + l15;
            const float bb = bob[col];
            #pragma unroll
            for (int r = 0; r < 4; ++r)
                BA[w][swf(q * 4 + r, col)] = fmaxf(acc[c][r] + bb, 0.f);
        }
    }
    {
        f32x4 acc[4] = {{0,0,0,0},{0,0,0,0},{0,0,0,0},{0,0,0,0}};
        gemm_lds(acc, BA[w], W4h, W4l, 2, 0, 2, l15, q, lane);
        if (!IS_POST2) {
            #pragma unroll
            for (int c = 0; c < 4; ++c) {
                const int col = c * 16 + l15;
                const float bb = b4[col];
                #pragma unroll
                for (int r = 0; r < 4; ++r) {
                    const int grow = rbase + q * 4 + r;
                    if (grow < N) A2[(size_t)grow * 64 + col] = f2bf(sf2 * (acc[c][r] + bb));
                }
            }
        } else {
            float w2c[4], bb4[4];
            #pragma unroll
            for (int c = 0; c < 4; ++c) {
                const int col = c * 16 + l15;
                w2c[c] = oW2[col];
                bb4[c] = b4[col];
            }
            #pragma unroll
            for (int r = 0; r < 4; ++r) {
                float s = 0.f;
                #pragma unroll
                for (int c = 0; c < 4; ++c)
                    s += fmaxf(acc[c][r] + bb4[c], 0.f) * w2c[c];
                s += __shfl_xor(s, 1);
                s += __shfl_xor(s, 2);
                s += __shfl_xor(s, 4);
                s += __shfl_xor(s, 8);
                const int grow = rbase + q * 4 + r;
                if (l15 == 0 && grow < N) out[grow] = s;
            }
        }
    }
}

// ---------------------------------------------------------------------------
// Multiblock scans (unchanged from R12)
// ---------------------------------------------------------------------------
__global__ __launch_bounds__(256)
void scanA2_kernel(const int* __restrict__ h1, int n1, int* __restrict__ cs1,
                   const int* __restrict__ h2, int n2, int* __restrict__ cs2)
{
    __shared__ int wsum[4];
    const int which = blockIdx.y;
    const int* h = which ? h2 : h1;
    const int n = which ? n2 : n1;
    int* csum = which ? cs2 : cs1;
    if (blockIdx.x * 4096 >= n) return;

    const int t = threadIdx.x, lane = t & 63, wid = t >> 6;
    const int base = blockIdx.x * 4096 + t * 16;
    int s = 0;
    #pragma unroll
    for (int j = 0; j < 16; ++j) {
        const int idx = base + j;
        if (idx < n) s += h[idx];
    }
    #pragma unroll
    for (int d = 1; d < 64; d <<= 1) s += __shfl_xor(s, d);
    if (lane == 0) wsum[wid] = s;
    __syncthreads();
    if (t == 0) csum[blockIdx.x] = wsum[0] + wsum[1] + wsum[2] + wsum[3];
}

__global__ __launch_bounds__(256)
void scanB2_kernel(int* __restrict__ cs1, int nch1, int* __restrict__ rs1, int n1,
                   int* __restrict__ cs2, int nch2, int* __restrict__ rs2, int n2)
{
    __shared__ int wsum[4];
    const int which = blockIdx.x;
    int* csum = which ? cs2 : cs1;
    const int nchunks = which ? nch2 : nch1;
    int* rs = which ? rs2 : rs1;
    const int n = which ? n2 : n1;

    const int t = threadIdx.x, lane = t & 63, wid = t >> 6;
    const int v = (t < nchunks) ? csum[t] : 0;
    int x = v;
    #pragma unroll
    for (int d = 1; d < 64; d <<= 1) { int y = __shfl_up(x, d); if (lane >= d) x += y; }
    if (lane == 63) wsum[wid] = x;
    __syncthreads();
    int woff = 0;
    for (int i = 0; i < wid; ++i) woff += wsum[i];
    if (t < nchunks) csum[t] = woff + x - v;
    if (t == 0) rs[n] = wsum[0] + wsum[1] + wsum[2] + wsum[3];
}

__global__ __launch_bounds__(256)
void scanC2_kernel(const int* __restrict__ h1, int n1, const int* __restrict__ cs1,
                   int* __restrict__ rs1,
                   const int* __restrict__ h2, int n2, const int* __restrict__ cs2,
                   int* __restrict__ rs2)
{
    __shared__ int wsum[4];
    const int which = blockIdx.y;
    const int* h = which ? h2 : h1;
    const int n = which ? n2 : n1;
    const int* csum = which ? cs2 : cs1;
    int* rs = which ? rs2 : rs1;
    if (blockIdx.x * 4096 >= n) return;

    const int t = threadIdx.x, lane = t & 63, wid = t >> 6;
    const int base = blockIdx.x * 4096 + t * 16;
    int loc[16];
    int s = 0;
    #pragma unroll
    for (int j = 0; j < 16; ++j) {
        loc[j] = s;
        const int idx = base + j;
        if (idx < n) s += h[idx];
    }
    int x = s;
    #pragma unroll
    for (int d = 1; d < 64; d <<= 1) { int y = __shfl_up(x, d); if (lane >= d) x += y; }
    if (lane == 63) wsum[wid] = x;
    __syncthreads();
    int woff = 0;
    for (int i = 0; i < wid; ++i) woff += wsum[i];
    const int toff = csum[blockIdx.x] + woff + x - s;
    #pragma unroll
    for (int j = 0; j < 16; ++j) {
        const int idx = base + j;
        if (idx < n) rs[idx] = toff + loc[j];
    }
}

// ---------------------------------------------------------------------------
// Atomic-free single-pass scatter (plain int2 stores — R12 semantics; the
// R14 nontemporal variant evicted pairs from L2 and starved agg's reads).
// ---------------------------------------------------------------------------
__global__ __launch_bounds__(256)
void scatter_kernel(const int* __restrict__ ei, int E,
                    const float* __restrict__ ef,
                    const float* __restrict__ eshp, const float* __restrict__ escp,
                    const unsigned int* __restrict__ rank,
                    const int* __restrict__ rs1, const int* __restrict__ rs2,
                    int2* __restrict__ pairs1, int2* __restrict__ pairs2)
{
    const int e = blockIdx.x * 256 + threadIdx.x;
    if (e >= E) return;
    const int i0 = ei[e];
    const int i1 = ei[E + e];
    const unsigned int rk = rank[e];
    const float en = (ef[e] - eshp[0]) * escp[0];
    const int enb = __float_as_int(en);
    const int pos1 = rs1[i0] + (int)(rk & 0xffffu);
    const int pos2 = rs2[i1] + (int)(rk >> 16);
    pairs1[pos1] = make_int2(i1, enb);
    pairs2[pos2] = make_int2(i0, enb);
}

// ---------------------------------------------------------------------------
// Gather-aggregate, 8-way unrolled (one row per wave; 200K-wave concurrency).
// ---------------------------------------------------------------------------
DEV void agg_body(int row, int j, const int* __restrict__ rs,
                  const int2* __restrict__ pairs,
                  const unsigned short* __restrict__ Ttgt,
                  const unsigned short* __restrict__ Tsrc,
                  const float* __restrict__ We, const float* __restrict__ sfp,
                  float* __restrict__ G)
{
    const float base = bf2f(Ttgt[(size_t)row * 64 + j]);
    const float sfWe = sfp[0] * We[j];
    const int s = rs[row];
    const int e = rs[row + 1];
    float acc = 0.f;
    int p = s;
    for (; p + 7 < e; p += 8) {
        int2 a[8];
        float b[8];
        #pragma unroll
        for (int u = 0; u < 8; ++u) a[u] = pairs[p + u];
        #pragma unroll
        for (int u = 0; u < 8; ++u) b[u] = bf2f(Tsrc[(size_t)a[u].x * 64 + j]);
        #pragma unroll
        for (int u = 0; u < 8; ++u)
            acc += fmaxf(base + b[u] + __int_as_float(a[u].y) * sfWe, 0.f);
    }
    for (; p < e; ++p) {
        const int2 pr = pairs[p];
        const float bs = bf2f(Tsrc[(size_t)pr.x * 64 + j]);
        acc += fmaxf(base + bs + __int_as_float(pr.y) * sfWe, 0.f);
    }
    G[(size_t)row * 64 + j] = acc;
}

__global__ __launch_bounds__(256)
void agg_kernel(int nrows, const int* __restrict__ rs,
                const int2* __restrict__ pairs,
                const unsigned short* __restrict__ Ttgt,
                const unsigned short* __restrict__ Tsrc,
                const float* __restrict__ We, const float* __restrict__ sfp,
                float* __restrict__ G)
{
    const int row = blockIdx.x * 4 + (int)(threadIdx.x >> 6);
    if (row >= nrows) return;
    agg_body(row, (int)(threadIdx.x & 63), rs, pairs, Ttgt, Tsrc, We, sfp, G);
}

// ---------------------------------------------------------------------------
extern "C" void kernel_launch(void* const* d_in, const int* in_sizes, int n_in,
                              void* d_out, int out_size, void* d_ws, size_t ws_size,
                              hipStream_t stream)
{
    const float* cf      = (const float*)d_in[0];
    const float* ef      = (const float*)d_in[1];
    const float* vf      = (const float*)d_in[2];
    const float* c_shift = (const float*)d_in[3];
    const float* c_scale = (const float*)d_in[4];
    const float* v_shift = (const float*)d_in[5];
    const float* v_scale = (const float*)d_in[6];
    const float* e_shift = (const float*)d_in[7];
    const float* e_scale = (const float*)d_in[8];
    const float* c_W1 = (const float*)d_in[9];
    const float* c_b1 = (const float*)d_in[10];
    const float* c_W2 = (const float*)d_in[11];
    const float* c_b2 = (const float*)d_in[12];
    const float* v_W1 = (const float*)d_in[13];
    const float* v_b1 = (const float*)d_in[14];
    const float* v_W2 = (const float*)d_in[15];
    const float* v_b2 = (const float*)d_in[16];
    const float* vc_Wl  = (const float*)d_in[17];
    const float* vc_bl  = (const float*)d_in[18];
    const float* vc_We  = (const float*)d_in[19];
    const float* vc_Wr  = (const float*)d_in[20];
    const float* vc_sf  = (const float*)d_in[21];
    const float* vc_Wf  = (const float*)d_in[22];
    const float* vc_bf  = (const float*)d_in[23];
    const float* vc_sp  = (const float*)d_in[24];
    const float* vc_Woa = (const float*)d_in[25];
    const float* vc_boa = (const float*)d_in[26];
    const float* vc_Wob = (const float*)d_in[27];
    const float* vc_bob = (const float*)d_in[28];
    const float* cv_Wl  = (const float*)d_in[29];
    const float* cv_bl  = (const float*)d_in[30];
    const float* cv_We  = (const float*)d_in[31];
    const float* cv_Wr  = (const float*)d_in[32];
    const float* cv_sf  = (const float*)d_in[33];
    const float* cv_Wf  = (const float*)d_in[34];
    const float* cv_bf  = (const float*)d_in[35];
    const float* cv_sp  = (const float*)d_in[36];
    const float* cv_Woa = (const float*)d_in[37];
    const float* cv_boa = (const float*)d_in[38];
    const float* cv_Wob = (const float*)d_in[39];
    const float* cv_bob = (const float*)d_in[40];
    const float* out_W1 = (const float*)d_in[41];
    const float* out_b1 = (const float*)d_in[42];
    const float* out_W2 = (const float*)d_in[43];
    const int*   eidx   = (const int*)d_in[44];

    const int NC = in_sizes[0] / 5;
    const int NV = in_sizes[2] / 19;
    const int E  = in_sizes[1];

    // ---- workspace layout (256B aligned slots) ----
    // ws budget ~256MB: rank aliases G2's slot (rank written by fused hist,
    // last read by scatter; G2 first written by agg2, strictly after).
    char* ws = (char*)d_ws;
    size_t off = 0;
    auto alloc = [&](size_t bytes) -> size_t {
        size_t o = off;
        off = (off + bytes + 255) & ~(size_t)255;
        return o;
    };
    size_t o_h1 = alloc((size_t)NC * 4);
    size_t o_h2 = alloc((size_t)NV * 4);
    size_t zero_bytes = off;
    size_t o_rs1  = alloc((size_t)(NC + 1) * 4);
    size_t o_rs2  = alloc((size_t)(NV + 1) * 4);
    size_t o_cs1  = alloc(256 * 4);
    size_t o_cs2  = alloc(256 * 4);
    size_t o_p1   = alloc((size_t)E * 8);
    size_t o_p2   = alloc((size_t)E * 8);
    size_t o_G1   = alloc((size_t)NC * 64 * 4);
    size_t o_G2   = alloc((size_t)NV * 64 * 4);  // also hosts rank[E] (u32) early
    size_t o_Emc  = alloc((size_t)NC * 64 * 4);
    size_t o_Emv  = alloc((size_t)NV * 64 * 4);
    size_t o_A1   = alloc((size_t)NC * 64 * 2);  // A2 aliases A1 (dead after agg1)
    size_t o_B1   = alloc((size_t)NV * 64 * 2);
    size_t o_B2   = alloc((size_t)NV * 64 * 2);

    static const int nkt_arr[NMAT] = {1,2,2,1,2,2,2,2,4,2,2,2,4,2,2};
    static const int KR_arr[NMAT]  = {5,64,64,19,64,64,64,64,128,64,64,64,128,64,64};
    const float* src_arr[NMAT] = {c_W1, c_W2, vc_Wl, v_W1, v_W2, vc_Wr, cv_Wr,
                                  vc_Wf, vc_Woa, vc_Wob, cv_Wl,
                                  cv_Wf, cv_Woa, cv_Wob, out_W1};
    size_t o_wh[NMAT], o_wl[NMAT];
    for (int m = 0; m < NMAT; ++m) {
        o_wh[m] = alloc((size_t)nkt_arr[m] * 4 * 64 * 8 * 2);
        o_wl[m] = alloc((size_t)nkt_arr[m] * 4 * 64 * 8 * 2);
    }
    (void)ws_size; (void)n_in; (void)out_size;

    int*  h1   = (int*)(ws + o_h1);
    int*  h2   = (int*)(ws + o_h2);
    int*  rs1  = (int*)(ws + o_rs1);
    int*  rs2  = (int*)(ws + o_rs2);
    int*  cs1  = (int*)(ws + o_cs1);
    int*  cs2  = (int*)(ws + o_cs2);
    unsigned int* rank = (unsigned int*)(ws + o_G2);   // alias: E*4 <= NV*256
    int2* p1   = (int2*)(ws + o_p1);
    int2* p2   = (int2*)(ws + o_p2);
    float* G1  = (float*)(ws + o_G1);
    float* G2  = (float*)(ws + o_G2);
    float* Emc = (float*)(ws + o_Emc);
    float* Emv = (float*)(ws + o_Emv);
    unsigned short* A1 = (unsigned short*)(ws + o_A1);
    unsigned short* B1 = (unsigned short*)(ws + o_B1);
    unsigned short* A2 = (unsigned short*)(ws + o_A1);  // alias
    unsigned short* B2 = (unsigned short*)(ws + o_B2);

    PrepArgs pa;
    for (int m = 0; m < NMAT; ++m) {
        pa.src[m] = src_arr[m];
        pa.hi[m] = (unsigned short*)(ws + o_wh[m]);
        pa.lo[m] = (unsigned short*)(ws + o_wl[m]);
        pa.nkt[m] = nkt_arr[m];
        pa.KR[m] = KR_arr[m];
    }
    auto WH = [&](int m) { return (const unsigned short*)(ws + o_wh[m]); };
    auto WL = [&](int m) { return (const unsigned short*)(ws + o_wl[m]); };

    hipMemsetAsync(ws, 0, zero_bytes, stream);

    // --- weight prep ---
    prep_kernel<<<dim3(4, NMAT), 256, 0, stream>>>(pa);

    // --- fused histogram(+rank) / embeddings ---
    const int tC = (NC + 63) >> 6, tV = (NV + 63) >> 6;
    const int nE = tC + tV;
    FusedArgs fa;
    fa.ei = eidx; fa.E = E; fa.nH = nE;
    fa.h1 = h1; fa.h2 = h2; fa.rank = rank;
    fa.tC = tC; fa.tV = tV;
    fa.cf = cf; fa.NC = NC; fa.c_shift = c_shift; fa.c_scale = c_scale;
    fa.vf = vf; fa.NV = NV; fa.v_shift = v_shift; fa.v_scale = v_scale;
    fa.cW1h = WH(0); fa.cW1l = WL(0); fa.cW2h = WH(1); fa.cW2l = WL(1);
    fa.cWt1h = WH(2); fa.cWt1l = WL(2);
    fa.vW1h = WH(3); fa.vW1l = WL(3); fa.vW2h = WH(4); fa.vW2l = WL(4);
    fa.vWt1h = WH(5); fa.vWt1l = WL(5); fa.vWt2h = WH(6); fa.vWt2l = WL(6);
    fa.c_b1 = c_b1; fa.c_b2 = c_b2; fa.v_b1 = v_b1; fa.v_b2 = v_b2;
    fa.vc_bl = vc_bl; fa.vc_sf = vc_sf; fa.cv_sf = cv_sf;
    fa.Emc = Emc; fa.Emv = Emv; fa.A1 = A1; fa.B1 = B1; fa.B2 = B2;
    fused_he_kernel<<<2 * nE, 256, 0, stream>>>(fa);

    // --- fused scans ---
    const int nch1 = (NC + 4095) / 4096, nch2 = (NV + 4095) / 4096;
    const int nchm = nch1 > nch2 ? nch1 : nch2;
    scanA2_kernel<<<dim3(nchm, 2), 256, 0, stream>>>(h1, NC, cs1, h2, NV, cs2);
    scanB2_kernel<<<2, 256, 0, stream>>>(cs1, nch1, rs1, NC, cs2, nch2, rs2, NV);
    scanC2_kernel<<<dim3(nchm, 2), 256, 0, stream>>>(h1, NC, cs1, rs1, h2, NV, cs2, rs2);

    // --- atomic-free single-pass scatter ---
    scatter_kernel<<<(E + 255) / 256, 256, 0, stream>>>(
        eidx, E, ef, e_shift, e_scale, rank, rs1, rs2, p1, p2);
    // rank (G2 slot) dead from here; agg2 overwrites G2 below.

    // --- conv1: target ei0 -> Ttgt=A1, Tsrc=B1 ---
    agg_kernel<<<(NC + 3) / 4, 256, 0, stream>>>(
        NC, rs1, p1, A1, B1, vc_We, vc_sf, G1);
    post_mfma<false><<<tC, 256, 0, stream>>>(
        NC, G1, rs1, Emc,
        WH(7), WL(7), vc_bf, vc_sp,
        WH(8), WL(8), vc_boa,
        WH(9), WL(9), vc_bob,
        WH(10), WL(10), cv_bl,
        cv_sf, A2, nullptr, nullptr);

    // --- conv2: target ei1 -> Ttgt=B2, Tsrc=A2 ---
    agg_kernel<<<(NV + 3) / 4, 256, 0, stream>>>(
        NV, rs2, p2, B2, A2, cv_We, cv_sf, G2);
    post_mfma<true><<<tV, 256, 0, stream>>>(
        NV, G2, rs2, Emv,
        WH(11), WL(11), cv_bf, cv_sp,
        WH(12), WL(12), cv_boa,
        WH(13), WL(13), cv_bob,
        WH(14), WL(14), out_b1,
        nullptr, nullptr, out_W2, (float*)d_out);
}